// Round 3
// baseline (228.449 us; speedup 1.0000x reference)
//
#include <hip/hip_runtime.h>

// MultiHeadSelfAttention  B=2 S=2048 D=1024 H=16 d=64, fp32 in/out.
// R11: attn register tile doubled: each wave owns 64 q-rows (2x 32-q subtiles)
//      sharing one set of K/V fragment reads -> MFMA:ds_read 2:1 (was 1:1),
//      per-CU LDS read traffic halved. Grid 256 = 1 block/CU, 4 waves.
//      ILP replaces TLP: 4 indep QK chains; SM(a) schedules under QK(b),
//      PV(a) under SM(b). setprio dropped (1 wave/SIMD).
//   Why: R10 counters: MfmaUtil 23% == exact MFMA floor (13.8us/58.9us);
//   LDS pipe ~1150cy/tile/CU bursty on every wave's critical path; VALU ~500.
// prep/gemm1/swizzle/gemm2 unchanged.
// ws: Ksw 8M @0 | val_h 8M @8M | wq_t 6M @16M | wo_t 2M @22M | qkv 24M @24M
//     | x_h 8M @48M (dead after GEMM1, overwritten by Vsw)

#define D_MODEL 1024
#define NHEAD   16
#define HDIM    64
#define SEQ     2048
#define BATCH   2
#define NTOK    (BATCH * SEQ)

typedef float    f32x4  __attribute__((ext_vector_type(4)));
typedef float    f32x16 __attribute__((ext_vector_type(16)));
typedef _Float16 f16x8  __attribute__((ext_vector_type(8)));
typedef _Float16 f16x4  __attribute__((ext_vector_type(4)));

#define GLOBAL_LOAD_LDS16(gptr, lptr)                                            \
    __builtin_amdgcn_global_load_lds(                                            \
        (const __attribute__((address_space(1))) unsigned int*)(gptr),           \
        (__attribute__((address_space(3))) unsigned int*)(lptr), 16, 0, 0)

// ---------------- prep: x->fp16, W_qkv^T, W_out^T (one launch) ----------------
__global__ __launch_bounds__(256) void prep_kernel(
    const float* __restrict__ x, _Float16* __restrict__ xh,
    const float* __restrict__ Wqkv, _Float16* __restrict__ wq_t,
    const float* __restrict__ Wout, _Float16* __restrict__ wo_t)
{
    const int bx = blockIdx.x;
    const int tid = threadIdx.x;
    if (bx < 4096) {
        const int i = (bx * 256 + tid) * 4;
        const float4 v = *(const float4*)&x[i];
        f16x4 hh;
        hh[0] = (_Float16)v.x; hh[1] = (_Float16)v.y;
        hh[2] = (_Float16)v.z; hh[3] = (_Float16)v.w;
        *(f16x4*)&xh[i] = hh;
        return;
    }
    __shared__ float ts[64][65];
    const float* W; _Float16* Wt; int N, n0, k0;
    if (bx < 4096 + 768) {
        const int local = bx - 4096;
        W = Wqkv; Wt = wq_t; N = 3072;
        n0 = (local % 48) * 64; k0 = (local / 48) * 64;
    } else {
        const int local = bx - 4864;
        W = Wout; Wt = wo_t; N = 1024;
        n0 = (local % 16) * 64; k0 = (local / 16) * 64;
    }
    {
        const int r = tid >> 2, c = (tid & 3) << 4;
        const float* src = W + (size_t)(k0 + r) * N + n0 + c;
        #pragma unroll
        for (int u = 0; u < 4; ++u)
            *(float4*)&ts[r][c + u * 4] = *(const float4*)&src[u * 4];
    }
    __syncthreads();
    {
        const int n = tid >> 2, kg = (tid & 3) << 4;
        f16x8 v0, v1;
        #pragma unroll
        for (int j = 0; j < 8; ++j) {
            v0[j] = (_Float16)ts[kg + j][n];
            v1[j] = (_Float16)ts[kg + 8 + j][n];
        }
        _Float16* dst = Wt + (size_t)(n0 + n) * D_MODEL + k0 + kg;
        *(f16x8*)&dst[0] = v0;
        *(f16x8*)&dst[8] = v1;
    }
}

// ---------------- GEMM1: 128x128 tile, BK=32, 512 threads (8 waves of 32x64) ----------------
__global__ __launch_bounds__(512) void gemm_qkv_kernel(
    const _Float16* __restrict__ A, const _Float16* __restrict__ Bt,
    const float* __restrict__ bias, _Float16* __restrict__ Cout,
    int M, int N, int K)
{
    __shared__ _Float16 lds[2][4096];     // A plane 8KB, B plane 8KB: [chunk4][row128][8]
    const int tid = threadIdx.x;
    const int wave = tid >> 6, lane = tid & 63;
    const int quad = lane >> 4, l16 = lane & 15;
    const int m0 = blockIdx.y * 128, n0 = blockIdx.x * 128;
    const int wr = wave >> 1, wc = wave & 1;       // wave tile: rows wr*32, cols wc*64

    f32x4 acc[2][4] = {};

    const bool isA = wave < 4;
    const _Float16* gsrc = isA ? (A + (size_t)m0 * K) : (Bt + (size_t)n0 * K);
    _Float16* ldst = isA ? &lds[0][0] : &lds[1][0];
    const int sbase = (wave & 3) * 2;              // 2 segments of 1KB per wave

    for (int k0 = 0; k0 < K; k0 += 32) {
        __syncthreads();
        #pragma unroll
        for (int j = 0; j < 2; ++j) {
            const int seg = sbase + j;
            const int chunk = seg >> 1;
            const int row = ((seg & 1) << 6) | lane;
            GLOBAL_LOAD_LDS16(gsrc + (size_t)row * K + k0 + chunk * 8, ldst + seg * 512);
        }
        __syncthreads();

        f16x8 a[2], b[4];
        #pragma unroll
        for (int mt = 0; mt < 2; ++mt)
            a[mt] = *(const f16x8*)&lds[0][quad * 1024 + (wr * 32 + mt * 16 + l16) * 8];
        #pragma unroll
        for (int nt = 0; nt < 4; ++nt)
            b[nt] = *(const f16x8*)&lds[1][quad * 1024 + (wc * 64 + nt * 16 + l16) * 8];
        #pragma unroll
        for (int mt = 0; mt < 2; ++mt)
            #pragma unroll
            for (int nt = 0; nt < 4; ++nt)
                acc[mt][nt] = __builtin_amdgcn_mfma_f32_16x16x32_f16(a[mt], b[nt], acc[mt][nt], 0, 0, 0);
    }

    #pragma unroll
    for (int nt = 0; nt < 4; ++nt) {
        const int col = n0 + wc * 64 + nt * 16 + l16;
        const float bv = bias[col];
        #pragma unroll
        for (int mt = 0; mt < 2; ++mt) {
            #pragma unroll
            for (int r = 0; r < 4; ++r) {
                const int row = m0 + wr * 32 + mt * 16 + quad * 4 + r;
                Cout[(size_t)row * N + col] = (_Float16)(acc[mt][nt][r] + bv);
            }
        }
    }
}

// ---------------- GEMM2: 128x64 tile, BK=32, 512 threads (8 waves of 32x32), fp32 out ----------------
__global__ __launch_bounds__(512) void gemm_out_kernel(
    const _Float16* __restrict__ A, const _Float16* __restrict__ Bt,
    const float* __restrict__ bias, float* __restrict__ Cout)
{
    const int K = D_MODEL, N = D_MODEL;
    __shared__ _Float16 ldsA[4096];       // [chunk4][row128][8] 8KB
    __shared__ _Float16 ldsB[2048];       // [chunk4][row64][8]  4KB
    const int tid = threadIdx.x;
    const int wave = tid >> 6, lane = tid & 63;
    const int quad = lane >> 4, l16 = lane & 15;
    const int m0 = blockIdx.y * 128, n0 = blockIdx.x * 64;
    const int wr = wave >> 1, wc = wave & 1;       // wave tile: rows wr*32, cols wc*32

    f32x4 acc[2][2] = {};

    for (int k0 = 0; k0 < K; k0 += 32) {
        __syncthreads();
        if (wave < 4) {
            #pragma unroll
            for (int j = 0; j < 2; ++j) {
                const int seg = wave * 2 + j;          // 0..7
                const int chunk = seg >> 1;
                const int row = ((seg & 1) << 6) | lane;
                GLOBAL_LOAD_LDS16(A + (size_t)(m0 + row) * K + k0 + chunk * 8, ldsA + seg * 512);
            }
        } else {
            const int seg = wave - 4;                  // 0..3 (chunk = seg, 64 rows)
            GLOBAL_LOAD_LDS16(Bt + (size_t)(n0 + lane) * K + k0 + seg * 8, ldsB + seg * 512);
        }
        __syncthreads();

        f16x8 a[2], b[2];
        #pragma unroll
        for (int mt = 0; mt < 2; ++mt)
            a[mt] = *(const f16x8*)&ldsA[quad * 1024 + (wr * 32 + mt * 16 + l16) * 8];
        #pragma unroll
        for (int nt = 0; nt < 2; ++nt)
            b[nt] = *(const f16x8*)&ldsB[quad * 512 + (wc * 32 + nt * 16 + l16) * 8];
        #pragma unroll
        for (int mt = 0; mt < 2; ++mt)
            #pragma unroll
            for (int nt = 0; nt < 2; ++nt)
                acc[mt][nt] = __builtin_amdgcn_mfma_f32_16x16x32_f16(a[mt], b[nt], acc[mt][nt], 0, 0, 0);
    }

    #pragma unroll
    for (int nt = 0; nt < 2; ++nt) {
        const int col = n0 + wc * 32 + nt * 16 + l16;
        const float bv = bias[col];
        #pragma unroll
        for (int mt = 0; mt < 2; ++mt) {
            #pragma unroll
            for (int r = 0; r < 4; ++r) {
                const int row = m0 + wr * 32 + mt * 16 + quad * 4 + r;
                Cout[(size_t)row * N + col] = acc[mt][nt][r] + bv;
            }
        }
    }
}

// ---------------- K,V slices of qkv -> swizzled MFMA-ready layouts ----------------
__global__ __launch_bounds__(256) void swizzle_kv_kernel(
    const _Float16* __restrict__ qkv,
    _Float16* __restrict__ Ksw, _Float16* __restrict__ Vsw)
{
    __shared__ _Float16 ts[64][72];
    const int tid = threadIdx.x;
    const int s0 = blockIdx.x * 64, h = blockIdx.y, b = blockIdx.z;
    const size_t hsz = (size_t)8 * SEQ * 8;
    _Float16* kh = Ksw + (size_t)(b * NHEAD + h) * hsz;
    _Float16* vh = Vsw + (size_t)(b * NHEAD + h) * hsz;

    {
        const int s = s0 + (tid >> 2);
        const int dg = (tid & 3) << 4;
        const _Float16* src = qkv + (size_t)(b * SEQ + s) * (3 * D_MODEL) + h * (3 * HDIM) + HDIM + dg;
        const f16x8 v0 = *(const f16x8*)&src[0];
        const f16x8 v1 = *(const f16x8*)&src[8];
        const int c0 = dg >> 3;
        *(f16x8*)&kh[((size_t)c0 * SEQ + s) * 8]       = v0;
        *(f16x8*)&kh[((size_t)(c0 + 1) * SEQ + s) * 8] = v1;
    }
    {
        const int s = tid >> 2, dg = (tid & 3) << 4;
        const _Float16* src = qkv + (size_t)(b * SEQ + s0 + s) * (3 * D_MODEL) + h * (3 * HDIM) + 2 * HDIM + dg;
        *(f16x8*)&ts[s][dg]     = *(const f16x8*)&src[0];
        *(f16x8*)&ts[s][dg + 8] = *(const f16x8*)&src[8];
    }
    __syncthreads();
    {
        const int d = tid >> 2, sg = (tid & 3) << 4;
        f16x8 v0, v1;
        #pragma unroll
        for (int j = 0; j < 8; ++j) { v0[j] = ts[sg + j][d]; v1[j] = ts[sg + 8 + j][d]; }
        const int cs0 = (s0 + sg) >> 3;
        *(f16x8*)&vh[((size_t)cs0 * HDIM + d) * 8]       = v0;
        *(f16x8*)&vh[((size_t)(cs0 + 1) * HDIM + d) * 8] = v1;
    }
}

// softmax fragment: s0/s1 (keys 0-31 / 32-63 scores for q=l31) -> 4 PV A-frags
// pa[ks][j] = P[q=l31][key = ks*16 + hi*8 + j], rs += sum of own 32 exp2's.
__device__ __forceinline__ void softmax_frag(
    const f32x16 s0, const f32x16 s1, float& rs, f16x8 pa[4])
{
    #pragma unroll
    for (int half = 0; half < 2; ++half) {
        const f32x16 sv = half ? s1 : s0;
        float p[16];
        #pragma unroll
        for (int r = 0; r < 16; ++r)
            p[r] = __builtin_amdgcn_exp2f(sv[r]);
        #pragma unroll
        for (int r = 0; r < 16; r += 4)
            rs += (p[r] + p[r + 1]) + (p[r + 2] + p[r + 3]);

        union { f16x8 hv; unsigned u[4]; } lo, hh;
        {
            const unsigned A = __builtin_bit_cast(unsigned, __builtin_amdgcn_cvt_pkrtz(p[0], p[1]));
            const unsigned B = __builtin_bit_cast(unsigned, __builtin_amdgcn_cvt_pkrtz(p[2], p[3]));
            const unsigned C = __builtin_bit_cast(unsigned, __builtin_amdgcn_cvt_pkrtz(p[4], p[5]));
            const unsigned D = __builtin_bit_cast(unsigned, __builtin_amdgcn_cvt_pkrtz(p[6], p[7]));
            const auto rac = __builtin_amdgcn_permlane32_swap(A, C, false, false);
            const auto rbd = __builtin_amdgcn_permlane32_swap(B, D, false, false);
            lo.u[0] = rac[0]; lo.u[1] = rbd[0]; lo.u[2] = rac[1]; lo.u[3] = rbd[1];
        }
        {
            const unsigned E = __builtin_bit_cast(unsigned, __builtin_amdgcn_cvt_pkrtz(p[8],  p[9]));
            const unsigned F = __builtin_bit_cast(unsigned, __builtin_amdgcn_cvt_pkrtz(p[10], p[11]));
            const unsigned G = __builtin_bit_cast(unsigned, __builtin_amdgcn_cvt_pkrtz(p[12], p[13]));
            const unsigned H = __builtin_bit_cast(unsigned, __builtin_amdgcn_cvt_pkrtz(p[14], p[15]));
            const auto reg = __builtin_amdgcn_permlane32_swap(E, G, false, false);
            const auto rfh = __builtin_amdgcn_permlane32_swap(F, H, false, false);
            hh.u[0] = reg[0]; hh.u[1] = rfh[0]; hh.u[2] = reg[1]; hh.u[3] = rfh[1];
        }
        pa[half * 2]     = lo.hv;
        pa[half * 2 + 1] = hh.hv;
    }
}

// ---------------- fp16 MFMA flash attention, 32x32, 64q/wave, QBLK=256 ----------
// Wave w owns q rows [q0+w*64, +64) as two 32-q subtiles (a: +0, b: +32).
// K-frags (kf) and V-frags (vf) are q-independent -> read ONCE, feed both
// subtiles: 16 ds_read_b128 -> 32 MFMAs per tile (2:1, was 1:1).
// 4 indep QK chains (sa0,sa1,sb0,sb1); SM(a) overlaps QK(b); PV(a) overlaps
// SM(b) -- single basic block, list scheduler interleaves VALU/MFMA pipes.
__global__ __launch_bounds__(256) void attn_mfma_kernel(
    const _Float16* __restrict__ qkv,
    const _Float16* __restrict__ Ksw, const _Float16* __restrict__ Vsw,
    _Float16* __restrict__ val)
{
    __shared__ _Float16 Ks[2][4096];      // [dchunk8][key64][8]  8KB x2
    __shared__ _Float16 Vts[2][4096];     // [kchunk8][d64][8]    8KB x2

    const int tid = threadIdx.x;
    const int wave = tid >> 6, lane = tid & 63;
    const int l31 = lane & 31, hi = lane >> 5;

    // XCD-chunked swizzle: 256 blocks, 32 per XCD = 4 heads x 8 qt -> K/V 2MB
    // per XCD stays L2-resident.
    const int id = blockIdx.x;
    const int g  = (id & 7) * 32 + (id >> 3);
    const int qt = g & 7, hb = g >> 3;
    const int h  = hb & 15, b = hb >> 4;
    const int q0 = qt * 256;

    const size_t hsz = (size_t)8 * SEQ * 8;
    const _Float16* kh = Ksw + (size_t)(b * NHEAD + h) * hsz;
    const _Float16* vh = Vsw + (size_t)(b * NHEAD + h) * hsz;

    // Q B-fragments for both subtiles: col=l31 -> q row, k = kk*16 + hi*8 + j
    f16x8 qfa[4], qfb[4];
    {
        const int rowa = q0 + wave * 64 + l31;
        const _Float16* srca = qkv + (size_t)(b * SEQ + rowa) * (3 * D_MODEL) + h * (3 * HDIM) + hi * 8;
        const _Float16* srcb = srca + (size_t)32 * (3 * D_MODEL);
        #pragma unroll
        for (int kk = 0; kk < 4; ++kk) {
            const f16x8 ta = *(const f16x8*)(srca + kk * 16);
            const f16x8 tb = *(const f16x8*)(srcb + kk * 16);
            #pragma unroll
            for (int j = 0; j < 8; ++j) {
                qfa[kk][j] = (_Float16)((float)ta[j] * 0.1803368802f);   // (1/8)*log2(e)
                qfb[kk][j] = (_Float16)((float)tb[j] * 0.1803368802f);
            }
        }
    }

    f32x16 acca0 = {}, acca1 = {};     // O[qa][d], d = l31 / 32+l31
    f32x16 accb0 = {}, accb1 = {};     // O[qb][d]
    float rsa = 0.f, rsb = 0.f;

    // prologue: stage tile 0 into buffer 0 (4 waves x 2 chunks each)
    #pragma unroll
    for (int jj = 0; jj < 2; ++jj) {
        const int c = wave * 2 + jj;
        GLOBAL_LOAD_LDS16(kh + ((size_t)c * SEQ + lane) * 8, &Ks[0][c * 512]);
        GLOBAL_LOAD_LDS16(vh + ((size_t)c * HDIM + lane) * 8, &Vts[0][c * 512]);
    }
    __syncthreads();

    for (int kt = 0; kt < SEQ / 64; ++kt) {
        const int cur = kt & 1;

        // stage tile kt+1 into the other buffer
        if (kt + 1 < SEQ / 64) {
            #pragma unroll
            for (int jj = 0; jj < 2; ++jj) {
                const int c = wave * 2 + jj;
                GLOBAL_LOAD_LDS16(kh + ((size_t)c * SEQ + (kt + 1) * 64 + lane) * 8,
                                  &Ks[cur ^ 1][c * 512]);
                GLOBAL_LOAD_LDS16(vh + ((size_t)((kt + 1) * 8 + c) * HDIM + lane) * 8,
                                  &Vts[cur ^ 1][c * 512]);
            }
        }

        // ---- K fragments: read once, feed both subtiles ----
        f16x8 kf0[4], kf1[4];
        #pragma unroll
        for (int kk = 0; kk < 4; ++kk) {
            kf0[kk] = *(const f16x8*)&Ks[cur][(kk * 2 + hi) * 512 + l31 * 8];
            kf1[kk] = *(const f16x8*)&Ks[cur][(kk * 2 + hi) * 512 + (32 + l31) * 8];
        }

        // ---- QK^T subtile a ----
        f32x16 sa0 = {}, sa1 = {};
        #pragma unroll
        for (int kk = 0; kk < 4; ++kk) {
            sa0 = __builtin_amdgcn_mfma_f32_32x32x16_f16(kf0[kk], qfa[kk], sa0, 0, 0, 0);
            sa1 = __builtin_amdgcn_mfma_f32_32x32x16_f16(kf1[kk], qfa[kk], sa1, 0, 0, 0);
        }

        // ---- V fragments (issue early; lgkm overlaps QK(b) MFMAs) ----
        f16x8 vf0[4], vf1[4];
        #pragma unroll
        for (int ks = 0; ks < 4; ++ks) {
            vf0[ks] = *(const f16x8*)&Vts[cur][(ks * 2 + hi) * 512 + l31 * 8];
            vf1[ks] = *(const f16x8*)&Vts[cur][(ks * 2 + hi) * 512 + (32 + l31) * 8];
        }

        // ---- QK^T subtile b (SM(a) VALU schedules under these MFMAs) ----
        f32x16 sb0 = {}, sb1 = {};
        #pragma unroll
        for (int kk = 0; kk < 4; ++kk) {
            sb0 = __builtin_amdgcn_mfma_f32_32x32x16_f16(kf0[kk], qfb[kk], sb0, 0, 0, 0);
            sb1 = __builtin_amdgcn_mfma_f32_32x32x16_f16(kf1[kk], qfb[kk], sb1, 0, 0, 0);
        }

        // ---- softmax a -> PV a (PV(a) MFMAs cover SM(b) VALU) ----
        f16x8 paa[4];
        softmax_frag(sa0, sa1, rsa, paa);
        #pragma unroll
        for (int ks = 0; ks < 4; ++ks) {
            acca0 = __builtin_amdgcn_mfma_f32_32x32x16_f16(paa[ks], vf0[ks], acca0, 0, 0, 0);
            acca1 = __builtin_amdgcn_mfma_f32_32x32x16_f16(paa[ks], vf1[ks], acca1, 0, 0, 0);
        }

        // ---- softmax b -> PV b ----
        f16x8 pab[4];
        softmax_frag(sb0, sb1, rsb, pab);
        #pragma unroll
        for (int ks = 0; ks < 4; ++ks) {
            accb0 = __builtin_amdgcn_mfma_f32_32x32x16_f16(pab[ks], vf0[ks], accb0, 0, 0, 0);
            accb1 = __builtin_amdgcn_mfma_f32_32x32x16_f16(pab[ks], vf1[ks], accb1, 0, 0, 0);
        }

        __syncthreads();
    }

    // per-sub row sums: lane holds half the keys; partner lane^32 the rest
    rsa += __shfl_xor(rsa, 32);
    rsb += __shfl_xor(rsb, 32);
    const float inva = 1.f / rsa;
    const float invb = 1.f / rsb;

    #pragma unroll
    for (int r = 0; r < 16; ++r) {
        const int qo = (r & 3) + 8 * (r >> 2) + 4 * hi;     // wave-local q row
        const float ia = __shfl(inva, qo);
        const float ib = __shfl(invb, qo);
        const int rowa = b * SEQ + q0 + wave * 64 + qo;
        const int rowb = rowa + 32;
        val[(size_t)rowa * D_MODEL + h * HDIM + l31]      = (_Float16)(acca0[r] * ia);
        val[(size_t)rowa * D_MODEL + h * HDIM + 32 + l31] = (_Float16)(acca1[r] * ia);
        val[(size_t)rowb * D_MODEL + h * HDIM + l31]      = (_Float16)(accb0[r] * ib);
        val[(size_t)rowb * D_MODEL + h * HDIM + 32 + l31] = (_Float16)(accb1[r] * ib);
    }
}

extern "C" void kernel_launch(void* const* d_in, const int* in_sizes, int n_in,
                              void* d_out, int out_size, void* d_ws, size_t ws_size,
                              hipStream_t stream)
{
    const float* x     = (const float*)d_in[0];
    const float* W_qkv = (const float*)d_in[1];
    const float* b_qkv = (const float*)d_in[2];
    const float* W_out = (const float*)d_in[3];
    const float* b_out = (const float*)d_in[4];

    char* ws = (char*)d_ws;
    _Float16* Ksw   = (_Float16*)ws;                      // [32][8][2048][8]  8 MiB
    _Float16* val_h = (_Float16*)(ws + (8u << 20));       // [4096][1024]      8 MiB
    _Float16* wq_t  = (_Float16*)(ws + (16u << 20));      // [3072][1024]      6 MiB
    _Float16* wo_t  = (_Float16*)(ws + (22u << 20));      // [1024][1024]      2 MiB
    _Float16* qkv_h = (_Float16*)(ws + (24u << 20));      // [4096][3072]     24 MiB
    _Float16* x_h   = (_Float16*)(ws + (48u << 20));      // [4096][1024]      8 MiB
    _Float16* Vsw   = (_Float16*)(ws + (48u << 20));      // overwrites dead x_h

    prep_kernel<<<5120, 256, 0, stream>>>(x, x_h, W_qkv, wq_t, W_out, wo_t);
    gemm_qkv_kernel<<<dim3(3 * D_MODEL / 128, NTOK / 128), 512, 0, stream>>>(
        x_h, wq_t, b_qkv, qkv_h, NTOK, 3 * D_MODEL, D_MODEL);
    swizzle_kv_kernel<<<dim3(SEQ / 64, NHEAD, BATCH), 256, 0, stream>>>(qkv_h, Ksw, Vsw);
    attn_mfma_kernel<<<dim3(256, 1, 1), 256, 0, stream>>>(qkv_h, Ksw, Vsw, val_h);
    gemm_out_kernel<<<dim3(D_MODEL / 64, NTOK / 128), 512, 0, stream>>>(
        val_h, wo_t, b_out, (float*)d_out);
}

// Round 4
// 216.634 us; speedup vs baseline: 1.0545x; 1.0545x over previous
//
#include <hip/hip_runtime.h>

// MultiHeadSelfAttention  B=2 S=2048 D=1024 H=16 d=64, fp32 in/out.
// R12: revert R11's 64q/wave (1 wave/SIMD was the regression: stalls exposed).
//      Keep R10's compute body (32q/wave, in-reg softmax via cvt_pkrtz+permlane,
//      2 waves/SIMD) and amortize per-tile fixed costs instead:
//        QBLK=256: one 8-wave block/CU (grid 256) -> one K/V LDS copy serves
//        8 waves (staging instr/wave halves, K/V L2 refetch halves);
//        KVBLK=128: two 64-key subtiles per barrier -> barriers 32->16.
//      LDS 64KB dbuf, 1 block/CU. setprio around MFMA clusters (T5).
//   Why: R10 counters: VALUBusy(47%) includes MFMA(23%) -> ~53% both-idle =
//   stall-bound on per-tile fixed costs (barrier drain+skew, staging issue).
// prep/gemm1/swizzle/gemm2 unchanged.
// ws: Ksw 8M @0 | val_h 8M @8M | wq_t 6M @16M | wo_t 2M @22M | qkv 24M @24M
//     | x_h 8M @48M (dead after GEMM1, overwritten by Vsw)

#define D_MODEL 1024
#define NHEAD   16
#define HDIM    64
#define SEQ     2048
#define BATCH   2
#define NTOK    (BATCH * SEQ)

typedef float    f32x4  __attribute__((ext_vector_type(4)));
typedef float    f32x16 __attribute__((ext_vector_type(16)));
typedef _Float16 f16x8  __attribute__((ext_vector_type(8)));
typedef _Float16 f16x4  __attribute__((ext_vector_type(4)));

#define GLOBAL_LOAD_LDS16(gptr, lptr)                                            \
    __builtin_amdgcn_global_load_lds(                                            \
        (const __attribute__((address_space(1))) unsigned int*)(gptr),           \
        (__attribute__((address_space(3))) unsigned int*)(lptr), 16, 0, 0)

// ---------------- prep: x->fp16, W_qkv^T, W_out^T (one launch) ----------------
__global__ __launch_bounds__(256) void prep_kernel(
    const float* __restrict__ x, _Float16* __restrict__ xh,
    const float* __restrict__ Wqkv, _Float16* __restrict__ wq_t,
    const float* __restrict__ Wout, _Float16* __restrict__ wo_t)
{
    const int bx = blockIdx.x;
    const int tid = threadIdx.x;
    if (bx < 4096) {
        const int i = (bx * 256 + tid) * 4;
        const float4 v = *(const float4*)&x[i];
        f16x4 hh;
        hh[0] = (_Float16)v.x; hh[1] = (_Float16)v.y;
        hh[2] = (_Float16)v.z; hh[3] = (_Float16)v.w;
        *(f16x4*)&xh[i] = hh;
        return;
    }
    __shared__ float ts[64][65];
    const float* W; _Float16* Wt; int N, n0, k0;
    if (bx < 4096 + 768) {
        const int local = bx - 4096;
        W = Wqkv; Wt = wq_t; N = 3072;
        n0 = (local % 48) * 64; k0 = (local / 48) * 64;
    } else {
        const int local = bx - 4864;
        W = Wout; Wt = wo_t; N = 1024;
        n0 = (local % 16) * 64; k0 = (local / 16) * 64;
    }
    {
        const int r = tid >> 2, c = (tid & 3) << 4;
        const float* src = W + (size_t)(k0 + r) * N + n0 + c;
        #pragma unroll
        for (int u = 0; u < 4; ++u)
            *(float4*)&ts[r][c + u * 4] = *(const float4*)&src[u * 4];
    }
    __syncthreads();
    {
        const int n = tid >> 2, kg = (tid & 3) << 4;
        f16x8 v0, v1;
        #pragma unroll
        for (int j = 0; j < 8; ++j) {
            v0[j] = (_Float16)ts[kg + j][n];
            v1[j] = (_Float16)ts[kg + 8 + j][n];
        }
        _Float16* dst = Wt + (size_t)(n0 + n) * D_MODEL + k0 + kg;
        *(f16x8*)&dst[0] = v0;
        *(f16x8*)&dst[8] = v1;
    }
}

// ---------------- GEMM1: 128x128 tile, BK=32, 512 threads (8 waves of 32x64) ----------------
__global__ __launch_bounds__(512) void gemm_qkv_kernel(
    const _Float16* __restrict__ A, const _Float16* __restrict__ Bt,
    const float* __restrict__ bias, _Float16* __restrict__ Cout,
    int M, int N, int K)
{
    __shared__ _Float16 lds[2][4096];     // A plane 8KB, B plane 8KB: [chunk4][row128][8]
    const int tid = threadIdx.x;
    const int wave = tid >> 6, lane = tid & 63;
    const int quad = lane >> 4, l16 = lane & 15;
    const int m0 = blockIdx.y * 128, n0 = blockIdx.x * 128;
    const int wr = wave >> 1, wc = wave & 1;       // wave tile: rows wr*32, cols wc*64

    f32x4 acc[2][4] = {};

    const bool isA = wave < 4;
    const _Float16* gsrc = isA ? (A + (size_t)m0 * K) : (Bt + (size_t)n0 * K);
    _Float16* ldst = isA ? &lds[0][0] : &lds[1][0];
    const int sbase = (wave & 3) * 2;              // 2 segments of 1KB per wave

    for (int k0 = 0; k0 < K; k0 += 32) {
        __syncthreads();
        #pragma unroll
        for (int j = 0; j < 2; ++j) {
            const int seg = sbase + j;
            const int chunk = seg >> 1;
            const int row = ((seg & 1) << 6) | lane;
            GLOBAL_LOAD_LDS16(gsrc + (size_t)row * K + k0 + chunk * 8, ldst + seg * 512);
        }
        __syncthreads();

        f16x8 a[2], b[4];
        #pragma unroll
        for (int mt = 0; mt < 2; ++mt)
            a[mt] = *(const f16x8*)&lds[0][quad * 1024 + (wr * 32 + mt * 16 + l16) * 8];
        #pragma unroll
        for (int nt = 0; nt < 4; ++nt)
            b[nt] = *(const f16x8*)&lds[1][quad * 1024 + (wc * 64 + nt * 16 + l16) * 8];
        #pragma unroll
        for (int mt = 0; mt < 2; ++mt)
            #pragma unroll
            for (int nt = 0; nt < 4; ++nt)
                acc[mt][nt] = __builtin_amdgcn_mfma_f32_16x16x32_f16(a[mt], b[nt], acc[mt][nt], 0, 0, 0);
    }

    #pragma unroll
    for (int nt = 0; nt < 4; ++nt) {
        const int col = n0 + wc * 64 + nt * 16 + l16;
        const float bv = bias[col];
        #pragma unroll
        for (int mt = 0; mt < 2; ++mt) {
            #pragma unroll
            for (int r = 0; r < 4; ++r) {
                const int row = m0 + wr * 32 + mt * 16 + quad * 4 + r;
                Cout[(size_t)row * N + col] = (_Float16)(acc[mt][nt][r] + bv);
            }
        }
    }
}

// ---------------- GEMM2: 128x64 tile, BK=32, 512 threads (8 waves of 32x32), fp32 out ----------------
__global__ __launch_bounds__(512) void gemm_out_kernel(
    const _Float16* __restrict__ A, const _Float16* __restrict__ Bt,
    const float* __restrict__ bias, float* __restrict__ Cout)
{
    const int K = D_MODEL, N = D_MODEL;
    __shared__ _Float16 ldsA[4096];       // [chunk4][row128][8] 8KB
    __shared__ _Float16 ldsB[2048];       // [chunk4][row64][8]  4KB
    const int tid = threadIdx.x;
    const int wave = tid >> 6, lane = tid & 63;
    const int quad = lane >> 4, l16 = lane & 15;
    const int m0 = blockIdx.y * 128, n0 = blockIdx.x * 64;
    const int wr = wave >> 1, wc = wave & 1;       // wave tile: rows wr*32, cols wc*32

    f32x4 acc[2][2] = {};

    for (int k0 = 0; k0 < K; k0 += 32) {
        __syncthreads();
        if (wave < 4) {
            #pragma unroll
            for (int j = 0; j < 2; ++j) {
                const int seg = wave * 2 + j;          // 0..7
                const int chunk = seg >> 1;
                const int row = ((seg & 1) << 6) | lane;
                GLOBAL_LOAD_LDS16(A + (size_t)(m0 + row) * K + k0 + chunk * 8, ldsA + seg * 512);
            }
        } else {
            const int seg = wave - 4;                  // 0..3 (chunk = seg, 64 rows)
            GLOBAL_LOAD_LDS16(Bt + (size_t)(n0 + lane) * K + k0 + seg * 8, ldsB + seg * 512);
        }
        __syncthreads();

        f16x8 a[2], b[2];
        #pragma unroll
        for (int mt = 0; mt < 2; ++mt)
            a[mt] = *(const f16x8*)&ldsA[quad * 1024 + (wr * 32 + mt * 16 + l16) * 8];
        #pragma unroll
        for (int nt = 0; nt < 2; ++nt)
            b[nt] = *(const f16x8*)&ldsB[quad * 512 + (wc * 32 + nt * 16 + l16) * 8];
        #pragma unroll
        for (int mt = 0; mt < 2; ++mt)
            #pragma unroll
            for (int nt = 0; nt < 2; ++nt)
                acc[mt][nt] = __builtin_amdgcn_mfma_f32_16x16x32_f16(a[mt], b[nt], acc[mt][nt], 0, 0, 0);
    }

    #pragma unroll
    for (int nt = 0; nt < 2; ++nt) {
        const int col = n0 + wc * 32 + nt * 16 + l16;
        const float bv = bias[col];
        #pragma unroll
        for (int mt = 0; mt < 2; ++mt) {
            #pragma unroll
            for (int r = 0; r < 4; ++r) {
                const int row = m0 + wr * 32 + mt * 16 + quad * 4 + r;
                Cout[(size_t)row * N + col] = acc[mt][nt][r] + bv;
            }
        }
    }
}

// ---------------- K,V slices of qkv -> swizzled MFMA-ready layouts ----------------
__global__ __launch_bounds__(256) void swizzle_kv_kernel(
    const _Float16* __restrict__ qkv,
    _Float16* __restrict__ Ksw, _Float16* __restrict__ Vsw)
{
    __shared__ _Float16 ts[64][72];
    const int tid = threadIdx.x;
    const int s0 = blockIdx.x * 64, h = blockIdx.y, b = blockIdx.z;
    const size_t hsz = (size_t)8 * SEQ * 8;
    _Float16* kh = Ksw + (size_t)(b * NHEAD + h) * hsz;
    _Float16* vh = Vsw + (size_t)(b * NHEAD + h) * hsz;

    {
        const int s = s0 + (tid >> 2);
        const int dg = (tid & 3) << 4;
        const _Float16* src = qkv + (size_t)(b * SEQ + s) * (3 * D_MODEL) + h * (3 * HDIM) + HDIM + dg;
        const f16x8 v0 = *(const f16x8*)&src[0];
        const f16x8 v1 = *(const f16x8*)&src[8];
        const int c0 = dg >> 3;
        *(f16x8*)&kh[((size_t)c0 * SEQ + s) * 8]       = v0;
        *(f16x8*)&kh[((size_t)(c0 + 1) * SEQ + s) * 8] = v1;
    }
    {
        const int s = tid >> 2, dg = (tid & 3) << 4;
        const _Float16* src = qkv + (size_t)(b * SEQ + s0 + s) * (3 * D_MODEL) + h * (3 * HDIM) + 2 * HDIM + dg;
        *(f16x8*)&ts[s][dg]     = *(const f16x8*)&src[0];
        *(f16x8*)&ts[s][dg + 8] = *(const f16x8*)&src[8];
    }
    __syncthreads();
    {
        const int d = tid >> 2, sg = (tid & 3) << 4;
        f16x8 v0, v1;
        #pragma unroll
        for (int j = 0; j < 8; ++j) { v0[j] = ts[sg + j][d]; v1[j] = ts[sg + 8 + j][d]; }
        const int cs0 = (s0 + sg) >> 3;
        *(f16x8*)&vh[((size_t)cs0 * HDIM + d) * 8]       = v0;
        *(f16x8*)&vh[((size_t)(cs0 + 1) * HDIM + d) * 8] = v1;
    }
}

// softmax fragment: s0/s1 (keys 0-31 / 32-63 scores for q=l31) -> 4 PV A-frags
// pa[ks][j] = P[q=l31][key = ks*16 + hi*8 + j], rs += sum of own 32 exp2's.
__device__ __forceinline__ void softmax_frag(
    const f32x16 s0, const f32x16 s1, float& rs, f16x8 pa[4])
{
    #pragma unroll
    for (int half = 0; half < 2; ++half) {
        const f32x16 sv = half ? s1 : s0;
        float p[16];
        #pragma unroll
        for (int r = 0; r < 16; ++r)
            p[r] = __builtin_amdgcn_exp2f(sv[r]);
        #pragma unroll
        for (int r = 0; r < 16; r += 4)
            rs += (p[r] + p[r + 1]) + (p[r + 2] + p[r + 3]);

        union { f16x8 hv; unsigned u[4]; } lo, hh;
        {
            const unsigned A = __builtin_bit_cast(unsigned, __builtin_amdgcn_cvt_pkrtz(p[0], p[1]));
            const unsigned B = __builtin_bit_cast(unsigned, __builtin_amdgcn_cvt_pkrtz(p[2], p[3]));
            const unsigned C = __builtin_bit_cast(unsigned, __builtin_amdgcn_cvt_pkrtz(p[4], p[5]));
            const unsigned D = __builtin_bit_cast(unsigned, __builtin_amdgcn_cvt_pkrtz(p[6], p[7]));
            const auto rac = __builtin_amdgcn_permlane32_swap(A, C, false, false);
            const auto rbd = __builtin_amdgcn_permlane32_swap(B, D, false, false);
            lo.u[0] = rac[0]; lo.u[1] = rbd[0]; lo.u[2] = rac[1]; lo.u[3] = rbd[1];
        }
        {
            const unsigned E = __builtin_bit_cast(unsigned, __builtin_amdgcn_cvt_pkrtz(p[8],  p[9]));
            const unsigned F = __builtin_bit_cast(unsigned, __builtin_amdgcn_cvt_pkrtz(p[10], p[11]));
            const unsigned G = __builtin_bit_cast(unsigned, __builtin_amdgcn_cvt_pkrtz(p[12], p[13]));
            const unsigned H = __builtin_bit_cast(unsigned, __builtin_amdgcn_cvt_pkrtz(p[14], p[15]));
            const auto reg = __builtin_amdgcn_permlane32_swap(E, G, false, false);
            const auto rfh = __builtin_amdgcn_permlane32_swap(F, H, false, false);
            hh.u[0] = reg[0]; hh.u[1] = rfh[0]; hh.u[2] = reg[1]; hh.u[3] = rfh[1];
        }
        pa[half * 2]     = lo.hv;
        pa[half * 2 + 1] = hh.hv;
    }
}

// ---------------- fp16 MFMA flash attention, 32x32, QBLK=256 (8 waves x 32q),
//                  KVBLK=128 (2x 64-key subtiles per barrier), dbuf K/V --------
// One 8-wave block per CU (grid 256): a single K/V LDS copy serves 8 waves.
// Per 128-key tile: 4 gload_lds/wave (was 8 across 2 blocks in R10), ONE
// barrier (was 2). Compute body per 64-key subtile identical to R10.
__global__ __launch_bounds__(512) void attn_mfma_kernel(
    const _Float16* __restrict__ qkv,
    const _Float16* __restrict__ Ksw, const _Float16* __restrict__ Vsw,
    _Float16* __restrict__ val)
{
    __shared__ _Float16 Ks[2][8192];      // [sub2][dchunk8][key64][8]  16KB x2
    __shared__ _Float16 Vts[2][8192];     // [sub2][kchunk8][d64][8]    16KB x2

    const int tid = threadIdx.x;
    const int wave = tid >> 6, lane = tid & 63;
    const int l31 = lane & 31, hi = lane >> 5;

    // XCD-chunked swizzle: 256 blocks, 32/XCD = 4 heads x 8 qt -> K/V 2MB/XCD
    const int id = blockIdx.x;
    const int g  = (id & 7) * 32 + (id >> 3);
    const int qt = g & 7, hb = g >> 3;
    const int h  = hb & 15, b = hb >> 4;
    const int q0 = qt * 256;

    const size_t hsz = (size_t)8 * SEQ * 8;
    const _Float16* kh = Ksw + (size_t)(b * NHEAD + h) * hsz;
    const _Float16* vh = Vsw + (size_t)(b * NHEAD + h) * hsz;

    // Q B-fragments: col=l31 -> q row, k = kk*16 + hi*8 + j
    f16x8 qf[4];
    {
        const int row = q0 + wave * 32 + l31;
        const _Float16* src = qkv + (size_t)(b * SEQ + row) * (3 * D_MODEL) + h * (3 * HDIM) + hi * 8;
        #pragma unroll
        for (int kk = 0; kk < 4; ++kk) {
            const f16x8 t = *(const f16x8*)(src + kk * 16);
            #pragma unroll
            for (int j = 0; j < 8; ++j)
                qf[kk][j] = (_Float16)((float)t[j] * 0.1803368802f);   // (1/8)*log2(e)
        }
    }

    f32x16 acc0 = {};      // O[q][d], dtile 0 (d = l31)
    f32x16 acc1 = {};      // dtile 1 (d = 32+l31)
    float rs = 0.f;

    // staging: 8 waves x 2 chunk-instrs each cover sub(2) x chunk(8) for K and V
    const int sidx0 = wave * 2;            // 0..14 even
    // prologue: stage 128-key tile 0 into buffer 0
    #pragma unroll
    for (int j = 0; j < 2; ++j) {
        const int idx = sidx0 + j;         // 0..15
        const int u = idx >> 3, c = idx & 7;
        GLOBAL_LOAD_LDS16(kh + ((size_t)c * SEQ + u * 64 + lane) * 8, &Ks[0][idx * 512]);
        GLOBAL_LOAD_LDS16(vh + ((size_t)(u * 8 + c) * HDIM + lane) * 8, &Vts[0][idx * 512]);
    }
    __syncthreads();

    for (int kt = 0; kt < SEQ / 128; ++kt) {
        const int cur = kt & 1;

        // stage tile kt+1 into the other buffer (readers of that buffer
        // finished before the end-of-(kt-1) barrier; end-of-kt barrier
        // drains vmcnt before it is read)
        if (kt + 1 < SEQ / 128) {
            #pragma unroll
            for (int j = 0; j < 2; ++j) {
                const int idx = sidx0 + j;
                const int u = idx >> 3, c = idx & 7;
                GLOBAL_LOAD_LDS16(kh + ((size_t)c * SEQ + (kt + 1) * 128 + u * 64 + lane) * 8,
                                  &Ks[cur ^ 1][idx * 512]);
                GLOBAL_LOAD_LDS16(vh + ((size_t)((kt + 1) * 16 + u * 8 + c) * HDIM + lane) * 8,
                                  &Vts[cur ^ 1][idx * 512]);
            }
        }

        // ---- two 64-key subtiles, compute body identical to R10 ----
        #pragma unroll
        for (int u = 0; u < 2; ++u) {
            const _Float16* ksub = &Ks[cur][u * 4096];
            const _Float16* vsub = &Vts[cur][u * 4096];

            // QK^T: S^T tiles (keytile 0: keys 0-31, keytile 1: keys 32-63)
            f32x16 s0 = {}, s1 = {};
            __builtin_amdgcn_s_setprio(1);
            #pragma unroll
            for (int kk = 0; kk < 4; ++kk) {
                const f16x8 k0 = *(const f16x8*)&ksub[(kk * 2 + hi) * 512 + l31 * 8];
                const f16x8 k1 = *(const f16x8*)&ksub[(kk * 2 + hi) * 512 + (32 + l31) * 8];
                s0 = __builtin_amdgcn_mfma_f32_32x32x16_f16(k0, qf[kk], s0, 0, 0, 0);
                s1 = __builtin_amdgcn_mfma_f32_32x32x16_f16(k1, qf[kk], s1, 0, 0, 0);
            }
            __builtin_amdgcn_s_setprio(0);

            // exp2 + in-register transpose to PV A-frags
            f16x8 pa[4];
            softmax_frag(s0, s1, rs, pa);

            // PV: O[q][d] += P[q][k] V[k][d], 4 ksteps of 16 keys
            __builtin_amdgcn_s_setprio(1);
            #pragma unroll
            for (int ks = 0; ks < 4; ++ks) {
                const f16x8 v0 = *(const f16x8*)&vsub[(ks * 2 + hi) * 512 + l31 * 8];
                const f16x8 v1 = *(const f16x8*)&vsub[(ks * 2 + hi) * 512 + (32 + l31) * 8];
                acc0 = __builtin_amdgcn_mfma_f32_32x32x16_f16(pa[ks], v0, acc0, 0, 0, 0);
                acc1 = __builtin_amdgcn_mfma_f32_32x32x16_f16(pa[ks], v1, acc1, 0, 0, 0);
            }
            __builtin_amdgcn_s_setprio(0);
        }

        __syncthreads();
    }

    // lane covers half the keys for q=l31; partner lane^32 has the complement
    rs += __shfl_xor(rs, 32);
    const float inv = 1.f / rs;

    #pragma unroll
    for (int r = 0; r < 16; ++r) {
        const int qo = (r & 3) + 8 * (r >> 2) + 4 * hi;     // wave-local q row
        const float invr = __shfl(inv, qo);                  // lane qo holds inv for q=qo
        const int row = b * SEQ + q0 + wave * 32 + qo;
        val[(size_t)row * D_MODEL + h * HDIM + l31]      = (_Float16)(acc0[r] * invr);
        val[(size_t)row * D_MODEL + h * HDIM + 32 + l31] = (_Float16)(acc1[r] * invr);
    }
}

extern "C" void kernel_launch(void* const* d_in, const int* in_sizes, int n_in,
                              void* d_out, int out_size, void* d_ws, size_t ws_size,
                              hipStream_t stream)
{
    const float* x     = (const float*)d_in[0];
    const float* W_qkv = (const float*)d_in[1];
    const float* b_qkv = (const float*)d_in[2];
    const float* W_out = (const float*)d_in[3];
    const float* b_out = (const float*)d_in[4];

    char* ws = (char*)d_ws;
    _Float16* Ksw   = (_Float16*)ws;                      // [32][8][2048][8]  8 MiB
    _Float16* val_h = (_Float16*)(ws + (8u << 20));       // [4096][1024]      8 MiB
    _Float16* wq_t  = (_Float16*)(ws + (16u << 20));      // [3072][1024]      6 MiB
    _Float16* wo_t  = (_Float16*)(ws + (22u << 20));      // [1024][1024]      2 MiB
    _Float16* qkv_h = (_Float16*)(ws + (24u << 20));      // [4096][3072]     24 MiB
    _Float16* x_h   = (_Float16*)(ws + (48u << 20));      // [4096][1024]      8 MiB
    _Float16* Vsw   = (_Float16*)(ws + (48u << 20));      // overwrites dead x_h

    prep_kernel<<<5120, 256, 0, stream>>>(x, x_h, W_qkv, wq_t, W_out, wo_t);
    gemm_qkv_kernel<<<dim3(3 * D_MODEL / 128, NTOK / 128), 512, 0, stream>>>(
        x_h, wq_t, b_qkv, qkv_h, NTOK, 3 * D_MODEL, D_MODEL);
    swizzle_kv_kernel<<<dim3(SEQ / 64, NHEAD, BATCH), 256, 0, stream>>>(qkv_h, Ksw, Vsw);
    attn_mfma_kernel<<<dim3(256, 1, 1), 512, 0, stream>>>(qkv_h, Ksw, Vsw, val_h);
    gemm_out_kernel<<<dim3(D_MODEL / 64, NTOK / 128), 512, 0, stream>>>(
        val_h, wo_t, b_out, (float*)d_out);
}